// Round 9
// baseline (291.134 us; speedup 1.0000x reference)
//
#include <hip/hip_runtime.h>

#define NVOX 20000
#define MPTS 64
#define CIN  10
#define NM   (NVOX*MPTS)      // 1,280,000
#define EPSBN 1e-3f

// ws param layout (float offsets) — only 512 floats used
#define WS_SCALE0 0     // 64
#define WS_SHIFT0 64    // 64
#define WS_SCALE1 128   // 128
#define WS_SHIFT1 256   // 128

// d_out doubles as stream-ordered scratch for reduction partials.
#define NB0   1024      // stats0 blocks -> P0 partials [NB0][P0STR]
#define P0STR 72
#define NBP   2500      // k_pass blocks; NITER voxels each, exact
#define NITER 8

typedef short bf16x8 __attribute__((ext_vector_type(8)));
typedef float f32x4  __attribute__((ext_vector_type(4)));
typedef unsigned int u32x4 __attribute__((ext_vector_type(4)));

__device__ __forceinline__ unsigned short f2bf(float f) {
    union { float f; unsigned u; } v; v.f = f;
    unsigned r = v.u + 0x7FFFu + ((v.u >> 16) & 1u);   // RNE to bf16
    return (unsigned short)(r >> 16);
}
// HW packed f32x2 -> bf16x2 (no builtin on gfx950)
__device__ __forceinline__ unsigned cvtpk(float lo, float hi) {
    unsigned d;
    asm("v_cvt_pk_bf16_f32 %0, %1, %2" : "=v"(d) : "v"(lo), "v"(hi));
    return d;
}
// packed u16 max: valid max for ReLU'd (non-negative) bf16 bit patterns
__device__ __forceinline__ unsigned pkmax(unsigned a, unsigned b) {
    unsigned d;
    asm("v_pk_max_u16 %0, %1, %2" : "=v"(d) : "v"(a), "v"(b));
    return d;
}

#define HARD_BARRIER()                                        \
    do {                                                      \
        asm volatile("s_waitcnt lgkmcnt(0)" ::: "memory");    \
        __builtin_amdgcn_sched_barrier(0);                    \
        __builtin_amdgcn_s_barrier();                         \
        __builtin_amdgcn_sched_barrier(0);                    \
    } while (0)

// x-moment pass: Sx (10) + Sxx (55 packed) via per-block partials, NO atomics.
__global__ __launch_bounds__(256) void k_stats0(const float* __restrict__ x,
                                                float* __restrict__ p0) {
    __shared__ float sm[4][P0STR];
    float sx[CIN];
    float sxx[55];
#pragma unroll
    for (int i = 0; i < CIN; i++) sx[i] = 0.f;
#pragma unroll
    for (int k = 0; k < 55; k++) sxx[k] = 0.f;

    const int t = threadIdx.x;
    const int tid = blockIdx.x * 256 + t;

    for (int g = tid; g < NM / 2; g += NB0 * 256) {
        const float4* xp = (const float4*)(x + (size_t)g * 20);
        float4 a = xp[0], b = xp[1], c = xp[2], d = xp[3], e = xp[4];
        float v0[CIN] = {a.x, a.y, a.z, a.w, b.x, b.y, b.z, b.w, c.x, c.y};
        float v1[CIN] = {c.z, c.w, d.x, d.y, d.z, d.w, e.x, e.y, e.z, e.w};
#pragma unroll
        for (int i = 0; i < CIN; i++) sx[i] += v0[i] + v1[i];
#pragma unroll
        for (int i = 0; i < CIN; i++)
#pragma unroll
            for (int j = 0; j <= i; j++)
                sxx[i * (i + 1) / 2 + j] += v0[i] * v0[j] + v1[i] * v1[j];
    }

    const int l = t & 63, w = t >> 6;
#pragma unroll
    for (int i = 0; i < CIN; i++) {
        float v = sx[i];
#pragma unroll
        for (int off = 32; off; off >>= 1) v += __shfl_xor(v, off, 64);
        if (l == 0) sm[w][i] = v;
    }
#pragma unroll
    for (int k = 0; k < 55; k++) {
        float v = sxx[k];
#pragma unroll
        for (int off = 32; off; off >>= 1) v += __shfl_xor(v, off, 64);
        if (l == 0) sm[w][10 + k] = v;
    }
    __syncthreads();
    if (t < 65)
        p0[blockIdx.x * P0STR + t] = sm[0][t] + sm[1][t] + sm[2][t] + sm[3][t];
}

__global__ void k_finalize0(const float* __restrict__ p0, float* __restrict__ ws,
                            const float* __restrict__ w0,
                            const float* __restrict__ gamma0, const float* __restrict__ beta0) {
    __shared__ float s[P0STR];
    const int t = threadIdx.x;
    if (t < 65) {
        float acc = 0.f;
#pragma unroll 8
        for (int r = 0; r < NB0; r++) acc += p0[r * P0STR + t];
        s[t] = acc;
    }
    __syncthreads();
    if (t < 64) {
        float w[CIN];
#pragma unroll
        for (int i = 0; i < CIN; i++) w[i] = w0[t * CIN + i];
        float m = 0.f;
#pragma unroll
        for (int i = 0; i < CIN; i++) m += w[i] * s[i];
        m *= (1.f / NM);
        float q = 0.f;
#pragma unroll
        for (int i = 0; i < CIN; i++)
#pragma unroll
            for (int j = 0; j <= i; j++)
                q += ((i == j) ? 1.f : 2.f) * w[i] * w[j] * s[10 + i * (i + 1) / 2 + j];
        q *= (1.f / NM);
        float var = q - m * m;
        float scale = gamma0[t] * rsqrtf(var + EPSBN);
        ws[WS_SCALE0 + t] = scale;
        ws[WS_SHIFT0 + t] = beta0[t] - m * scale;
    }
}

__global__ void k_finalize1(const float* __restrict__ p1, float* __restrict__ ws,
                            const float* __restrict__ gamma1, const float* __restrict__ beta1) {
    __shared__ float sm[2][4];
    const int c = blockIdx.x;
    const int t = threadIdx.x, l = t & 63, w = t >> 6;
    float s = 0.f, qq = 0.f;
    for (int r = t; r < NBP; r += 256) {
        s  += p1[(size_t)r * 256 + c];
        qq += p1[(size_t)r * 256 + 128 + c];
    }
#pragma unroll
    for (int off = 32; off; off >>= 1) { s += __shfl_xor(s, off, 64); qq += __shfl_xor(qq, off, 64); }
    if (l == 0) { sm[0][w] = s; sm[1][w] = qq; }
    __syncthreads();
    if (t == 0) {
        float S = sm[0][0] + sm[0][1] + sm[0][2] + sm[0][3];
        float Q = sm[1][0] + sm[1][1] + sm[1][2] + sm[1][3];
        float m = S * (1.f / NM);
        float var = Q * (1.f / NM) - m * m;
        float scale = gamma1[c] * rsqrtf(var + EPSBN);
        ws[WS_SCALE1 + c] = scale;
        ws[WS_SHIFT1 + c] = beta1[c] - m * scale;
    }
}

// Proven-safe two-barrier pipeline (R5/R7 ordering) + double-buffered zB/aggP + BN1 fold.
// Per iteration k (buf = k&1):
//   PRODUCE(voxel k+1 -> buf^1)          [L0 MFMA, zB writes, wave-local AGG, aggP write]
//   B_a (lgkm drain + sched_barrier + s_barrier)
//   consume-LOADS(voxel k from buf)      [bz, gp ds_reads]
//   B_b (same)
//   consume-COMPUTE(voxel k)             [gf fold, MFMA GEMM, epilogue]
// Every cross-wave hazard pair (produce-writes vs consume-reads, WAR on buffer reuse)
// is separated by a barrier in ALL interleavings — robust even if the scheduler hoists
// loads past the raw s_barrier (the R8 failure mechanism). BN1: wfrag pre-scaled by sc1
// (FINAL only), sh1 injected as the dacc C-init.
template <bool STATS>
__global__ __launch_bounds__(256) void k_pass(const float* __restrict__ x,
                                              const float* __restrict__ w0,
                                              const float* __restrict__ w1,
                                              const float* __restrict__ ws,
                                              float* __restrict__ pout) {
    __shared__ unsigned short zB[2][MPTS * 72];   // 18432 B  [buf][p][ch]
    __shared__ unsigned short aggP[2][4 * 64];    // 1024 B
    __shared__ float pbuf[256];                   // 1024 B (STATS staging)

    const int t  = threadIdx.x;
    const int l  = t & 63;
    const int w  = t >> 6;
    const int lr = l & 15;
    const int lg = l >> 4;
    const int prow = 16 * w + lr;                 // this lane's point row (produce)

    // W0 fragments, BN0 folded: A rows ch = 16mi+lr, k = 8lg+j (k10 = shift, rest 0)
    bf16x8 w0f[4];
#pragma unroll
    for (int mi = 0; mi < 4; mi++) {
        int ch = 16 * mi + lr;
        float sc = ws[WS_SCALE0 + ch], sh = ws[WS_SHIFT0 + ch];
        bf16x8 f;
#pragma unroll
        for (int j = 0; j < 8; j++) {
            int k = 8 * lg + j;
            float v = (k < CIN) ? sc * w0[ch * CIN + k] : (k == CIN ? sh : 0.f);
            f[j] = (short)f2bf(v);
        }
        w0f[mi] = f;
    }

    // W1 fragments: B cols o = 32w+16njl+lr, k = 32ks+8lg+j.
    // FINAL: rows pre-scaled by sc1[o]; shift goes into the dacc init.
    float sh1[2];
    bf16x8 wfrag[2][4];
#pragma unroll
    for (int njl = 0; njl < 2; njl++) {
        int col = 32 * w + 16 * njl + lr;
        float scl = 1.f;
        if constexpr (!STATS) {
            scl = ws[WS_SCALE1 + col];
            sh1[njl] = ws[WS_SHIFT1 + col];
        } else {
            sh1[njl] = 0.f;
        }
        const float* wrow = w1 + col * 128;
#pragma unroll
        for (int ks = 0; ks < 4; ks++) {
            float4 a = *(const float4*)(wrow + 32 * ks + 8 * lg);
            float4 b = *(const float4*)(wrow + 32 * ks + 8 * lg + 4);
            bf16x8 f;
            f[0] = (short)f2bf(scl * a.x); f[1] = (short)f2bf(scl * a.y);
            f[2] = (short)f2bf(scl * a.z); f[3] = (short)f2bf(scl * a.w);
            f[4] = (short)f2bf(scl * b.x); f[5] = (short)f2bf(scl * b.y);
            f[6] = (short)f2bf(scl * b.z); f[7] = (short)f2bf(scl * b.w);
            wfrag[njl][ks] = f;
        }
    }

    float as_[2] = {0.f, 0.f}, aq[2] = {0.f, 0.f};

    float2 pfA, pfB, pfC, pfD;
    auto PF = [&](int n) {
        const float* xr = x + (size_t)n * 640 + prow * CIN;
        if (lg == 0) {
            pfA = *(const float2*)(xr + 0); pfB = *(const float2*)(xr + 2);
            pfC = *(const float2*)(xr + 4); pfD = *(const float2*)(xr + 6);
        } else if (lg == 1) {
            pfA = *(const float2*)(xr + 8);
        }
    };
    auto MKBX = [&]() -> bf16x8 {
        u32x4 u = {0u, 0u, 0u, 0u};
        if (lg == 0) {
            u[0] = cvtpk(pfA.x, pfA.y); u[1] = cvtpk(pfB.x, pfB.y);
            u[2] = cvtpk(pfC.x, pfC.y); u[3] = cvtpk(pfD.x, pfD.y);
        } else if (lg == 1) {
            u[0] = cvtpk(pfA.x, pfA.y);
            u[1] = 0x00003F80u;       // k10 = 1.0 (shift lane), k11 = 0
        }
        return __builtin_bit_cast(bf16x8, u);
    };
    // PRODUCE voxel into buf: L0 (4 MFMA + ReLU/pack + wave-private zB writes) then
    // AGG (wave-local readback + packed butterfly -> aggP partial).
    auto PRODUCE = [&](bf16x8 bx, int buf) {
#pragma unroll
        for (int mi = 0; mi < 4; mi++) {
            f32x4 zz = {0.f, 0.f, 0.f, 0.f};
            f32x4 a0 = __builtin_amdgcn_mfma_f32_16x16x32_bf16(w0f[mi], bx, zz, 0, 0, 0);
            uint2 dd = { cvtpk(fmaxf(a0[0], 0.f), fmaxf(a0[1], 0.f)),
                         cvtpk(fmaxf(a0[2], 0.f), fmaxf(a0[3], 0.f)) };
            *(uint2*)&zB[buf][prow * 72 + 16 * mi + 4 * lg] = dd;  // ch 16mi+4lg..+3
        }
        int cs = l & 7;
        int pa = 16 * w + 2 * (l >> 3);
        u32x4 ra = *(const u32x4*)&zB[buf][pa * 72 + cs * 8];
        u32x4 rb = *(const u32x4*)&zB[buf][(pa + 1) * 72 + cs * 8];
        u32x4 m;
#pragma unroll
        for (int k2 = 0; k2 < 4; k2++) m[k2] = pkmax(ra[k2], rb[k2]);
#pragma unroll
        for (int off = 8; off <= 32; off <<= 1)
#pragma unroll
            for (int k2 = 0; k2 < 4; k2++) m[k2] = pkmax(m[k2], __shfl_xor(m[k2], off));
        if (l < 8) *(u32x4*)&aggP[buf][w * 64 + l * 8] = m;
    };

    // prologue: produce voxel 0 into buf 0 (fenced from iter-0 loads by B_a(0))
    PF(blockIdx.x);
    bf16x8 bx0 = MKBX();
    PF(blockIdx.x + NBP);
    PRODUCE(bx0, 0);

    for (int k = 0; k < NITER; k++) {
        const int buf = k & 1;
        const int n = blockIdx.x + k * NBP;

        // ---- PRODUCE voxel k+1 into buf^1 ----
        if (k < NITER - 1) {
            bf16x8 bx = MKBX();
            if (k < NITER - 2) PF(blockIdx.x + (k + 2) * NBP);
            PRODUCE(bx, buf ^ 1);
        }

        HARD_BARRIER();   // B_a: zB/aggP[buf] (written iter k-1 / prologue) ready

        // ---- consume-LOADS for voxel k (buf) ----
        bf16x8 bz[4][2];
#pragma unroll
        for (int pj = 0; pj < 4; pj++)
#pragma unroll
            for (int ks = 0; ks < 2; ks++)
                bz[pj][ks] = *(const bf16x8*)&zB[buf][(16 * pj + lr) * 72 + (4 * ks + lg) * 8];
        u32x4 gp[2][4];
#pragma unroll
        for (int ks = 0; ks < 2; ks++) {
            int sl = (4 * ks + lg) * 8;
#pragma unroll
            for (int wv = 0; wv < 4; wv++)
                gp[ks][wv] = *(const u32x4*)&aggP[buf][wv * 64 + sl];
        }

        HARD_BARRIER();   // B_b: buf reads drained; next iter may overwrite buf

        // ---- consume-COMPUTE voxel k ----
        bf16x8 gf[2];
#pragma unroll
        for (int ks = 0; ks < 2; ks++) {
            u32x4 g = gp[ks][0];
#pragma unroll
            for (int wv = 1; wv < 4; wv++)
#pragma unroll
                for (int k2 = 0; k2 < 4; k2++) g[k2] = pkmax(g[k2], gp[ks][wv][k2]);
            gf[ks] = __builtin_bit_cast(bf16x8, g);
        }
        f32x4 dacc[2];
#pragma unroll
        for (int njl = 0; njl < 2; njl++) {
            f32x4 zz = {sh1[njl], sh1[njl], sh1[njl], sh1[njl]};
            zz = __builtin_amdgcn_mfma_f32_16x16x32_bf16(gf[0], wfrag[njl][2], zz, 0, 0, 0);
            dacc[njl] = __builtin_amdgcn_mfma_f32_16x16x32_bf16(gf[1], wfrag[njl][3], zz, 0, 0, 0);
        }
#pragma unroll
        for (int njl = 0; njl < 2; njl++) {
            float vm = 0.f;
#pragma unroll
            for (int mi = 0; mi < 4; mi++) {
                f32x4 acc = dacc[njl];
                acc = __builtin_amdgcn_mfma_f32_16x16x32_bf16(bz[mi][0], wfrag[njl][0], acc, 0, 0, 0);
                acc = __builtin_amdgcn_mfma_f32_16x16x32_bf16(bz[mi][1], wfrag[njl][1], acc, 0, 0, 0);
                if (STATS) {
#pragma unroll
                    for (int r = 0; r < 4; r++) { as_[njl] += acc[r]; aq[njl] += acc[r] * acc[r]; }
                } else {
#pragma unroll
                    for (int r = 0; r < 4; r++) vm = fmaxf(vm, fmaxf(acc[r], 0.f));
                }
            }
            if (!STATS) {
                vm = fmaxf(vm, __shfl_xor(vm, 16));
                vm = fmaxf(vm, __shfl_xor(vm, 32));
                if (l < 16) pout[(size_t)n * 128 + 32 * w + 16 * njl + l] = vm;
            }
        }
    }

    if (STATS) {
        // disjoint cols across waves -> single staging array, one coalesced store
#pragma unroll
        for (int njl = 0; njl < 2; njl++) {
            float s = as_[njl];
            s += __shfl_xor(s, 16); s += __shfl_xor(s, 32);
            float qq = aq[njl];
            qq += __shfl_xor(qq, 16); qq += __shfl_xor(qq, 32);
            if (l < 16) {
                int col = 32 * w + 16 * njl + l;
                pbuf[col] = s;
                pbuf[128 + col] = qq;
            }
        }
        __syncthreads();
        pout[(size_t)blockIdx.x * 256 + t] = pbuf[t];
    }
}

extern "C" void kernel_launch(void* const* d_in, const int* in_sizes, int n_in,
                              void* d_out, int out_size, void* d_ws, size_t ws_size,
                              hipStream_t stream) {
    (void)in_sizes; (void)n_in; (void)out_size; (void)ws_size;
    const float* x      = (const float*)d_in[0];
    const float* W0     = (const float*)d_in[1];
    const float* gamma0 = (const float*)d_in[2];
    const float* beta0  = (const float*)d_in[3];
    const float* W1     = (const float*)d_in[4];
    const float* gamma1 = (const float*)d_in[5];
    const float* beta1  = (const float*)d_in[6];
    float* out = (float*)d_out;
    float* ws  = (float*)d_ws;

    k_stats0<<<NB0, 256, 0, stream>>>(x, out);                       // partials -> out
    k_finalize0<<<1, 256, 0, stream>>>(out, ws, W0, gamma0, beta0);
    k_pass<true><<<NBP, 256, 0, stream>>>(x, W0, W1, ws, out);       // partials -> out
    k_finalize1<<<128, 256, 0, stream>>>(out, ws, gamma1, beta1);
    k_pass<false><<<NBP, 256, 0, stream>>>(x, W0, W1, ws, out);      // final output
}